// Round 1
// baseline (46322.220 us; speedup 1.0000x reference)
//
#include <hip/hip_runtime.h>
#include <hip/hip_cooperative_groups.h>

namespace cg = cooperative_groups;

// Problem constants: B=64, T=512, I=H=1024, L=2  (all fp32)
// d_out = y2 [64,512,1024] ++ h_last [2,64,1024]
// d_ws  = xw [64,512,1024] ++ hbuf [2,64,1024]   (needs ~129 MB)

// ---------------------------------------------------------------------------
// proj: C[M,1024] = A[M,1024] @ W[1024,1024]^T + (b1 + b2)
// 128x128 tile, 256 threads, 8x8 micro-tile, BK=16, global prefetch.
// ---------------------------------------------------------------------------
__global__ __launch_bounds__(256) void proj_kernel(
    const float* __restrict__ A, const float* __restrict__ W,
    const float* __restrict__ b1, const float* __restrict__ b2,
    float* __restrict__ C)
{
    constexpr int Kd = 1024;
    constexpr int Nd = 1024;
    const int n0 = blockIdx.x * 128;
    const int m0 = blockIdx.y * 128;
    __shared__ float As[16 * 128];
    __shared__ float Bs[16 * 128];
    const int tid = threadIdx.x;
    const int tx = tid & 15;        // micro col group
    const int ty = tid >> 4;        // micro row group
    const int lrow = tid >> 2;      // staging row 0..63
    const int lj = (tid & 3) << 2;  // staging k 0,4,8,12

    float acc[8][8];
#pragma unroll
    for (int u = 0; u < 8; ++u)
#pragma unroll
        for (int v = 0; v < 8; ++v) acc[u][v] = 0.f;

    const float* Ab0 = A + (long long)(m0 + lrow) * Kd + lj;
    const float* Ab1 = Ab0 + 64ll * Kd;
    const float* Bb0 = W + (long long)(n0 + lrow) * Kd + lj;
    const float* Bb1 = Bb0 + 64ll * Kd;

    float4 pa0 = *(const float4*)(Ab0);
    float4 pa1 = *(const float4*)(Ab1);
    float4 pb0 = *(const float4*)(Bb0);
    float4 pb1 = *(const float4*)(Bb1);

    for (int kk = 0; kk < Kd; kk += 16) {
        __syncthreads();
        As[(lj + 0) * 128 + lrow] = pa0.x;
        As[(lj + 1) * 128 + lrow] = pa0.y;
        As[(lj + 2) * 128 + lrow] = pa0.z;
        As[(lj + 3) * 128 + lrow] = pa0.w;
        As[(lj + 0) * 128 + 64 + lrow] = pa1.x;
        As[(lj + 1) * 128 + 64 + lrow] = pa1.y;
        As[(lj + 2) * 128 + 64 + lrow] = pa1.z;
        As[(lj + 3) * 128 + 64 + lrow] = pa1.w;
        Bs[(lj + 0) * 128 + lrow] = pb0.x;
        Bs[(lj + 1) * 128 + lrow] = pb0.y;
        Bs[(lj + 2) * 128 + lrow] = pb0.z;
        Bs[(lj + 3) * 128 + lrow] = pb0.w;
        Bs[(lj + 0) * 128 + 64 + lrow] = pb1.x;
        Bs[(lj + 1) * 128 + 64 + lrow] = pb1.y;
        Bs[(lj + 2) * 128 + 64 + lrow] = pb1.z;
        Bs[(lj + 3) * 128 + 64 + lrow] = pb1.w;
        __syncthreads();

        // prefetch next chunk (wraps harmlessly on last iter)
        const int kk2 = (kk + 16) & (Kd - 1);
        pa0 = *(const float4*)(Ab0 + kk2);
        pa1 = *(const float4*)(Ab1 + kk2);
        pb0 = *(const float4*)(Bb0 + kk2);
        pb1 = *(const float4*)(Bb1 + kk2);

#pragma unroll
        for (int k = 0; k < 16; ++k) {
            const float4 va0 = *(const float4*)&As[k * 128 + (ty << 2)];
            const float4 va1 = *(const float4*)&As[k * 128 + 64 + (ty << 2)];
            const float4 vb0 = *(const float4*)&Bs[k * 128 + (tx << 2)];
            const float4 vb1 = *(const float4*)&Bs[k * 128 + 64 + (tx << 2)];
            const float av[8] = {va0.x, va0.y, va0.z, va0.w,
                                 va1.x, va1.y, va1.z, va1.w};
            const float bv[8] = {vb0.x, vb0.y, vb0.z, vb0.w,
                                 vb1.x, vb1.y, vb1.z, vb1.w};
#pragma unroll
            for (int u = 0; u < 8; ++u)
#pragma unroll
                for (int v = 0; v < 8; ++v) acc[u][v] += av[u] * bv[v];
        }
    }

    const int cn0 = n0 + (tx << 2);
    const float4 p0 = *(const float4*)(b1 + cn0);
    const float4 q0 = *(const float4*)(b2 + cn0);
    const float4 p1 = *(const float4*)(b1 + cn0 + 64);
    const float4 q1 = *(const float4*)(b2 + cn0 + 64);
    const float bias[8] = {p0.x + q0.x, p0.y + q0.y, p0.z + q0.z, p0.w + q0.w,
                           p1.x + q1.x, p1.y + q1.y, p1.z + q1.z, p1.w + q1.w};
#pragma unroll
    for (int u = 0; u < 8; ++u) {
        const int row = m0 + ((u < 4) ? ((ty << 2) + u) : (64 + (ty << 2) + (u - 4)));
        float* Cp = C + (long long)row * Nd;
        *(float4*)(Cp + cn0) =
            make_float4(acc[u][0] + bias[0], acc[u][1] + bias[1],
                        acc[u][2] + bias[2], acc[u][3] + bias[3]);
        *(float4*)(Cp + cn0 + 64) =
            make_float4(acc[u][4] + bias[4], acc[u][5] + bias[5],
                        acc[u][6] + bias[6], acc[u][7] + bias[7]);
    }
}

// ---------------------------------------------------------------------------
// rnn: persistent cooperative kernel. 256 WGs x 256 threads.
// WG wid: row group g = wid>>6 (16 batch rows), col slice m = wid&63 (16 cols).
// W_hh slice (16 cols x 1024 k) lives in LDS (exactly 64 KB), packed as
// float4 groups [k4][c][4] so the 16-lane c-read is 2-way-bank-aliased (free).
// h ping-pongs between two global buffers; one grid.sync() per time step.
// ---------------------------------------------------------------------------
__global__ __launch_bounds__(256) void rnn_kernel(
    const float* __restrict__ xw, const float* __restrict__ Whh,
    float* __restrict__ hbuf, float* __restrict__ y, float* __restrict__ hlast)
{
    __shared__ float Wl[16384];  // 64 KB: Wl[(k>>2)*64 + c*4 + (k&3)] = Whh[c0+c][k]
    const int wid = blockIdx.x;
    const int g = wid >> 6;      // 0..3
    const int m = wid & 63;      // 0..63
    const int c0 = m << 4;
    const int tid = threadIdx.x;

    for (int idx = tid; idx < 16384; idx += 256) {
        const int c = idx >> 10;
        const int k = idx & 1023;
        Wl[((k >> 2) << 6) + (c << 2) + (k & 3)] =
            Whh[(long long)(c0 + c) * 1024 + k];
    }
    __syncthreads();

    const int rl = tid >> 4;     // 0..15
    const int cl = tid & 15;     // 0..15
    const int r = (g << 4) + rl; // batch row 0..63
    const int c = c0 + cl;       // hidden col 0..1023

    cg::grid_group grid = cg::this_grid();

    const float* xwp = xw + (long long)r * 512 * 1024 + c;
    float* yp = y + (long long)r * 512 * 1024 + c;
    const float4* wv = (const float4*)Wl + cl;  // element (k4*16 + cl)

    for (int t = 0; t < 512; ++t) {
        const float* hin = hbuf + ((t & 1) << 16);
        float* hout = hbuf + (((t + 1) & 1) << 16);

        float acc = xwp[t << 10];
        const float4* hv4 = (const float4*)(hin + (r << 10));
#pragma unroll 8
        for (int k4 = 0; k4 < 256; ++k4) {
            const float4 w = wv[k4 << 4];
            const float4 h = hv4[k4];
            acc += w.x * h.x + w.y * h.y + w.z * h.z + w.w * h.w;
        }
        const float hn = tanhf(acc);
        hout[(r << 10) + c] = hn;
        yp[t << 10] = hn;
        if (t == 511) hlast[(r << 10) + c] = hn;
        grid.sync();
    }
}

// ---------------------------------------------------------------------------
extern "C" void kernel_launch(void* const* d_in, const int* in_sizes, int n_in,
                              void* d_out, int out_size, void* d_ws, size_t ws_size,
                              hipStream_t stream)
{
    const float* X    = (const float*)d_in[0];
    const float* Wih0 = (const float*)d_in[1];
    const float* bih0 = (const float*)d_in[2];
    const float* Whh0 = (const float*)d_in[3];
    const float* bhh0 = (const float*)d_in[4];
    const float* Wih1 = (const float*)d_in[5];
    const float* bih1 = (const float*)d_in[6];
    const float* Whh1 = (const float*)d_in[7];
    const float* bhh1 = (const float*)d_in[8];

    float* y     = (float*)d_out;        // [64,512,1024]
    float* hlast = y + 33554432ll;       // [2,64,1024]
    float* xw    = (float*)d_ws;         // [64,512,1024]
    float* hbuf  = xw + 33554432ll;      // [2,64,1024] ping-pong h state

    const dim3 pgrid(8, 256), pblock(256);
    const dim3 rgrid(256), rblock(256);

    // ---- layer 0 ----
    hipMemsetAsync(hbuf, 0, 2ll * 64 * 1024 * sizeof(float), stream);
    hipLaunchKernelGGL(proj_kernel, pgrid, pblock, 0, stream,
                       X, Wih0, bih0, bhh0, xw);
    {
        const float* xw_c = xw;
        float* hl0 = hlast;
        void* args0[] = {(void*)&xw_c, (void*)&Whh0, (void*)&hbuf,
                         (void*)&y, (void*)&hl0};
        hipLaunchCooperativeKernel((void*)rnn_kernel, rgrid, rblock, args0, 0, stream);
    }

    // ---- layer 1 (y1 now sits in d_out; xw scratch is reused) ----
    hipMemsetAsync(hbuf, 0, 2ll * 64 * 1024 * sizeof(float), stream);
    hipLaunchKernelGGL(proj_kernel, pgrid, pblock, 0, stream,
                       (const float*)y, Wih1, bih1, bhh1, xw);
    {
        const float* xw_c = xw;
        float* hl1 = hlast + 65536;
        void* args1[] = {(void*)&xw_c, (void*)&Whh1, (void*)&hbuf,
                         (void*)&y, (void*)&hl1};
        hipLaunchCooperativeKernel((void*)rnn_kernel, rgrid, rblock, args1, 0, stream);
    }
}

// Round 2
// 37780.707 us; speedup vs baseline: 1.2261x; 1.2261x over previous
//
#include <hip/hip_runtime.h>
#include <hip/hip_cooperative_groups.h>

namespace cg = cooperative_groups;

// Problem constants: B=64, T=512, I=H=1024, L=2  (all fp32)
// d_out = y [64,512,1024] ++ h_last [2,64,1024]
// d_ws  = xw [64,512,1024] ++ hq [2][256][64] float4 ++ flags [4*64] int

#define FLAG_LD(p)    __hip_atomic_load((p), __ATOMIC_RELAXED, __HIP_MEMORY_SCOPE_AGENT)
#define FLAG_ST(p, v) __hip_atomic_store((p), (v), __ATOMIC_RELAXED, __HIP_MEMORY_SCOPE_AGENT)

// ---------------------------------------------------------------------------
// proj: C[M,1024] = A[M,1024] @ W[1024,1024]^T + (b1 + b2)
// 128x128 tile, 256 threads, 8x8 micro-tile, BK=16, global prefetch.
// ---------------------------------------------------------------------------
__global__ __launch_bounds__(256) void proj_kernel(
    const float* __restrict__ A, const float* __restrict__ W,
    const float* __restrict__ b1, const float* __restrict__ b2,
    float* __restrict__ C)
{
    constexpr int Kd = 1024;
    constexpr int Nd = 1024;
    const int n0 = blockIdx.x * 128;
    const int m0 = blockIdx.y * 128;
    __shared__ float As[16 * 128];
    __shared__ float Bs[16 * 128];
    const int tid = threadIdx.x;
    const int tx = tid & 15;
    const int ty = tid >> 4;
    const int lrow = tid >> 2;
    const int lj = (tid & 3) << 2;

    float acc[8][8];
#pragma unroll
    for (int u = 0; u < 8; ++u)
#pragma unroll
        for (int v = 0; v < 8; ++v) acc[u][v] = 0.f;

    const float* Ab0 = A + (long long)(m0 + lrow) * Kd + lj;
    const float* Ab1 = Ab0 + 64ll * Kd;
    const float* Bb0 = W + (long long)(n0 + lrow) * Kd + lj;
    const float* Bb1 = Bb0 + 64ll * Kd;

    float4 pa0 = *(const float4*)(Ab0);
    float4 pa1 = *(const float4*)(Ab1);
    float4 pb0 = *(const float4*)(Bb0);
    float4 pb1 = *(const float4*)(Bb1);

    for (int kk = 0; kk < Kd; kk += 16) {
        __syncthreads();
        As[(lj + 0) * 128 + lrow] = pa0.x;
        As[(lj + 1) * 128 + lrow] = pa0.y;
        As[(lj + 2) * 128 + lrow] = pa0.z;
        As[(lj + 3) * 128 + lrow] = pa0.w;
        As[(lj + 0) * 128 + 64 + lrow] = pa1.x;
        As[(lj + 1) * 128 + 64 + lrow] = pa1.y;
        As[(lj + 2) * 128 + 64 + lrow] = pa1.z;
        As[(lj + 3) * 128 + 64 + lrow] = pa1.w;
        Bs[(lj + 0) * 128 + lrow] = pb0.x;
        Bs[(lj + 1) * 128 + lrow] = pb0.y;
        Bs[(lj + 2) * 128 + lrow] = pb0.z;
        Bs[(lj + 3) * 128 + lrow] = pb0.w;
        Bs[(lj + 0) * 128 + 64 + lrow] = pb1.x;
        Bs[(lj + 1) * 128 + 64 + lrow] = pb1.y;
        Bs[(lj + 2) * 128 + 64 + lrow] = pb1.z;
        Bs[(lj + 3) * 128 + 64 + lrow] = pb1.w;
        __syncthreads();

        const int kk2 = (kk + 16) & (Kd - 1);
        pa0 = *(const float4*)(Ab0 + kk2);
        pa1 = *(const float4*)(Ab1 + kk2);
        pb0 = *(const float4*)(Bb0 + kk2);
        pb1 = *(const float4*)(Bb1 + kk2);

#pragma unroll
        for (int k = 0; k < 16; ++k) {
            const float4 va0 = *(const float4*)&As[k * 128 + (ty << 2)];
            const float4 va1 = *(const float4*)&As[k * 128 + 64 + (ty << 2)];
            const float4 vb0 = *(const float4*)&Bs[k * 128 + (tx << 2)];
            const float4 vb1 = *(const float4*)&Bs[k * 128 + 64 + (tx << 2)];
            const float av[8] = {va0.x, va0.y, va0.z, va0.w,
                                 va1.x, va1.y, va1.z, va1.w};
            const float bv[8] = {vb0.x, vb0.y, vb0.z, vb0.w,
                                 vb1.x, vb1.y, vb1.z, vb1.w};
#pragma unroll
            for (int u = 0; u < 8; ++u)
#pragma unroll
                for (int v = 0; v < 8; ++v) acc[u][v] += av[u] * bv[v];
        }
    }

    const int cn0 = n0 + (tx << 2);
    const float4 p0 = *(const float4*)(b1 + cn0);
    const float4 q0 = *(const float4*)(b2 + cn0);
    const float4 p1 = *(const float4*)(b1 + cn0 + 64);
    const float4 q1 = *(const float4*)(b2 + cn0 + 64);
    const float bias[8] = {p0.x + q0.x, p0.y + q0.y, p0.z + q0.z, p0.w + q0.w,
                           p1.x + q1.x, p1.y + q1.y, p1.z + q1.z, p1.w + q1.w};
#pragma unroll
    for (int u = 0; u < 8; ++u) {
        const int row = m0 + ((u < 4) ? ((ty << 2) + u) : (64 + (ty << 2) + (u - 4)));
        float* Cp = C + (long long)row * Nd;
        *(float4*)(Cp + cn0) =
            make_float4(acc[u][0] + bias[0], acc[u][1] + bias[1],
                        acc[u][2] + bias[2], acc[u][3] + bias[3]);
        *(float4*)(Cp + cn0 + 64) =
            make_float4(acc[u][4] + bias[4], acc[u][5] + bias[5],
                        acc[u][6] + bias[6], acc[u][7] + bias[7]);
    }
}

// ---------------------------------------------------------------------------
// rnn v2: 4 independent teams (16 batch rows each) x 64 WGs (16 cols each).
// Wave = 16 rows x 4 cols: W read from LDS is 4 addrs x 16-lane broadcast
// (free); h stored k-transposed in global: hq[buf][k4][row] float4, so each
// lane's h load is one coalesced b128 and stores coalesce to 256B segments.
// Team barrier: per-WG generation flags, lane-parallel poll + __all.
// ---------------------------------------------------------------------------
__global__ __launch_bounds__(256) void rnn_kernel(
    const float* __restrict__ xw, const float* __restrict__ Whh,
    float4* __restrict__ hq,      // [2][256][64] float4
    float* __restrict__ y, float* __restrict__ hlast,
    int* __restrict__ flags)      // [4][64]
{
    __shared__ float4 Wl[4096];   // [k4=256][cl=16]; Wl[k4][cl][j] = Whh[c0+cl][4*k4+j]
    const int wid = blockIdx.x;
    const int team = wid >> 6;    // 0..3
    const int m = wid & 63;       // 0..63
    const int c0 = m << 4;
    const int tid = threadIdx.x;
    const int w = tid >> 6;       // wave 0..3
    const int lane = tid & 63;
    const int r_l = lane & 15;
    const int c_lo = lane >> 4;            // 0..3
    const int r = (team << 4) + r_l;       // batch row 0..63
    const int c = c0 + (w << 2) + c_lo;    // hidden col 0..1023

    // Stage W slice into LDS (coalesced along k).
    float* Wlf = (float*)Wl;
    for (int idx = tid; idx < 16384; idx += 256) {
        const int cl = idx >> 10;
        const int k = idx & 1023;
        Wlf[((((k >> 2) << 4) + cl) << 2) + (k & 3)] =
            Whh[(long long)(c0 + cl) * 1024 + k];
    }
    __syncthreads();

    const float* xwp = xw + ((long long)r << 19) + c;   // r*512*1024 + c
    float* yp = y + ((long long)r << 19) + c;
    int* tflags = flags + (team << 6);
    const int* myflag = tflags + lane;
    const float4* wcol = Wl + (w << 2) + c_lo;          // + k4*16
    const int pq = ((c >> 2) << 6) + r;                 // producer float4 index
    const int pc = c & 3;

    float xw_cur = xwp[0];

    for (int t = 0; t < 512; ++t) {
        // prefetch next xw before the barrier wait (overlaps poll latency)
        float xw_next = (t < 511) ? xwp[(long long)(t + 1) << 10] : 0.f;

        if (t > 0) {
            // wait until all 64 team producers have published h(t)
            while (true) {
                int f = FLAG_LD(myflag);
                if (__all(f >= t)) break;
            }
            __threadfence();   // acquire: invalidate stale cached h lines
        }

        const float4* hv = hq + ((t & 1) << 14) + r;    // buffer t&1
        float4 a0 = make_float4(xw_cur, 0.f, 0.f, 0.f);
        float4 a1 = make_float4(0.f, 0.f, 0.f, 0.f);
#pragma unroll 4
        for (int k4 = 0; k4 < 256; k4 += 2) {
            const float4 h0 = hv[(k4 << 6)];
            const float4 w0 = wcol[(k4 << 4)];
            const float4 h1 = hv[((k4 + 1) << 6)];
            const float4 w1 = wcol[((k4 + 1) << 4)];
            a0.x = fmaf(w0.x, h0.x, a0.x);
            a0.y = fmaf(w0.y, h0.y, a0.y);
            a0.z = fmaf(w0.z, h0.z, a0.z);
            a0.w = fmaf(w0.w, h0.w, a0.w);
            a1.x = fmaf(w1.x, h1.x, a1.x);
            a1.y = fmaf(w1.y, h1.y, a1.y);
            a1.z = fmaf(w1.z, h1.z, a1.z);
            a1.w = fmaf(w1.w, h1.w, a1.w);
        }
        const float s = ((a0.x + a1.x) + (a0.y + a1.y)) +
                        ((a0.z + a1.z) + (a0.w + a1.w));
        const float hn = tanhf(s);

        // publish h(t+1) (k-transposed, coalesced) + y
        float* hqs = (float*)(hq + (((t + 1) & 1) << 14));
        hqs[(pq << 2) + pc] = hn;
        yp[(long long)t << 10] = hn;
        if (t == 511) hlast[(r << 10) + c] = hn;

        __syncthreads();                 // drains WG stores (vmcnt) to L2
        if (tid == 0) {
            __threadfence();             // release: push to agent scope
            FLAG_ST(tflags + m, t + 1);
        }
        xw_cur = xw_next;
    }
}

// ---------------------------------------------------------------------------
extern "C" void kernel_launch(void* const* d_in, const int* in_sizes, int n_in,
                              void* d_out, int out_size, void* d_ws, size_t ws_size,
                              hipStream_t stream)
{
    const float* X    = (const float*)d_in[0];
    const float* Wih0 = (const float*)d_in[1];
    const float* bih0 = (const float*)d_in[2];
    const float* Whh0 = (const float*)d_in[3];
    const float* bhh0 = (const float*)d_in[4];
    const float* Wih1 = (const float*)d_in[5];
    const float* bih1 = (const float*)d_in[6];
    const float* Whh1 = (const float*)d_in[7];
    const float* bhh1 = (const float*)d_in[8];

    float* y     = (float*)d_out;          // [64,512,1024]
    float* hlast = y + 33554432ll;         // [2,64,1024]
    float* xw    = (float*)d_ws;           // [64,512,1024]
    float4* hq   = (float4*)(xw + 33554432ll);       // [2][256][64] float4 = 512 KB
    int* flags   = (int*)(hq + 32768);               // [4][64] = 1 KB

    const dim3 pgrid(8, 256), pblock(256);
    const dim3 rgrid(256), rblock(256);

    // ---- layer 0 ----
    hipMemsetAsync(hq, 0, 32768 * sizeof(float4), stream);
    hipMemsetAsync(flags, 0, 256 * sizeof(int), stream);
    hipLaunchKernelGGL(proj_kernel, pgrid, pblock, 0, stream,
                       X, Wih0, bih0, bhh0, xw);
    {
        const float* xw_c = xw;
        float* hl0 = hlast;
        void* args0[] = {(void*)&xw_c, (void*)&Whh0, (void*)&hq,
                         (void*)&y, (void*)&hl0, (void*)&flags};
        hipLaunchCooperativeKernel((void*)rnn_kernel, rgrid, rblock, args0, 0, stream);
    }

    // ---- layer 1 ----
    hipMemsetAsync(hq, 0, 32768 * sizeof(float4), stream);
    hipMemsetAsync(flags, 0, 256 * sizeof(int), stream);
    hipLaunchKernelGGL(proj_kernel, pgrid, pblock, 0, stream,
                       (const float*)y, Wih1, bih1, bhh1, xw);
    {
        const float* xw_c = xw;
        float* hl1 = hlast + 65536;
        void* args1[] = {(void*)&xw_c, (void*)&Whh1, (void*)&hq,
                         (void*)&y, (void*)&hl1, (void*)&flags};
        hipLaunchCooperativeKernel((void*)rnn_kernel, rgrid, rblock, args1, 0, stream);
    }
}